// Round 6
// baseline (95.055 us; speedup 1.0000x reference)
//
#include <hip/hip_runtime.h>

#define DDIM 128
#define ACC_BLOCKS 2048   // 2048 blocks x 4 waves = 8192 waves
#define RED_BLOCKS 64

typedef unsigned int uint;
typedef unsigned short ushort;

static __device__ __forceinline__ ushort f2bf(float x) {
    uint u = __float_as_uint(x);
    u += 0x7fffu + ((u >> 16) & 1u);   // RTN-even
    return (ushort)(u >> 16);
}
static __device__ __forceinline__ float bflo(uint u) { return __uint_as_float(u << 16); }
static __device__ __forceinline__ float bfhi(uint u) { return __uint_as_float(u & 0xffff0000u); }

// ---------------- Kernel 0: CSR rowptr from sorted segment ids ----------------
__global__ __launch_bounds__(256) void build_rowptr(
    const int* __restrict__ segs, int* __restrict__ rowptr, int N, int E)
{
    const int e = blockIdx.x * blockDim.x + threadIdx.x;
    if (e >= E) return;
    const int sc = segs[e];
    const int sp = (e == 0) ? -1 : segs[e - 1];
    for (int i = sp + 1; i <= sc; ++i) rowptr[i] = e;
    if (e == E - 1) {
        for (int i = sc + 1; i <= N; ++i) rowptr[i] = E;
    }
}

// ---------------- Kernel 1: Wh[t]=W@h[t], Mh[t]=M@h[t] -> bf16 tables ----------------
__global__ __launch_bounds__(128) void precompute_wh_mh(
    const float* __restrict__ impact,
    const float* __restrict__ W,
    const float* __restrict__ Mm,
    ushort* __restrict__ WhB,
    ushort* __restrict__ MhB,
    int T)
{
    __shared__ float hrow[8][DDIM];
    const int d = threadIdx.x;
    const int row0 = blockIdx.x * 8;
    const int rmax = min(8, T - row0);
    if (rmax <= 0) return;

    for (int r = 0; r < rmax; ++r)
        hrow[r][d] = impact[(size_t)(row0 + r) * DDIM + d];
    __syncthreads();

    const float4* __restrict__ W4 = reinterpret_cast<const float4*>(W) + (size_t)d * 32;
    const float4* __restrict__ M4 = reinterpret_cast<const float4*>(Mm) + (size_t)d * 32;
    const float4* __restrict__ H4 = reinterpret_cast<const float4*>(&hrow[0][0]);

    float accW[8], accM[8];
#pragma unroll
    for (int r = 0; r < 8; ++r) { accW[r] = 0.f; accM[r] = 0.f; }

    for (int kq = 0; kq < 32; ++kq) {
        const float4 wv = W4[kq];
        const float4 mv = M4[kq];
#pragma unroll
        for (int r = 0; r < 8; ++r) {
            const float4 hv = H4[r * 32 + kq];
            accW[r] = fmaf(hv.x, wv.x, accW[r]);
            accW[r] = fmaf(hv.y, wv.y, accW[r]);
            accW[r] = fmaf(hv.z, wv.z, accW[r]);
            accW[r] = fmaf(hv.w, wv.w, accW[r]);
            accM[r] = fmaf(hv.x, mv.x, accM[r]);
            accM[r] = fmaf(hv.y, mv.y, accM[r]);
            accM[r] = fmaf(hv.z, mv.z, accM[r]);
            accM[r] = fmaf(hv.w, mv.w, accM[r]);
        }
    }
    for (int r = 0; r < rmax; ++r) {
        WhB[(size_t)(row0 + r) * DDIM + d] = f2bf(accW[r]);
        MhB[(size_t)(row0 + r) * DDIM + d] = f2bf(accM[r]);
    }
}

// ---------------- Kernel 2: edge-balanced gather-sum + relu + block partial ----------------
// Wave owns nodes i with rowptr[i] in [t0,t1), t boundaries equal-edge-spaced.
// Lane holds one uint = 2 bf16 features; one wave gather = 256B row. Unroll 16.
__global__ __launch_bounds__(256) void accumulate_nodes(
    const uint* __restrict__ WhU,
    const uint* __restrict__ MhU,
    const int* __restrict__ node_ids,
    const int* __restrict__ neighbor_ids,
    const int* __restrict__ rowptr,
    float* __restrict__ partials,
    int N, int E)
{
    const int lane = threadIdx.x & 63;
    const int wv   = threadIdx.x >> 6;
    const int wg   = blockIdx.x * 4 + wv;
    const int nw   = (int)gridDim.x * 4;

    const int t0 = (int)(((long long)wg       * ((long long)E + 1)) / nw);
    const int t1 = (int)(((long long)(wg + 1) * ((long long)E + 1)) / nw);

    // lower_bound over rowptr[0..N]
    int lo = 0, hi = N + 1;
    while (lo < hi) { const int mid = (lo + hi) >> 1; if (rowptr[mid] < t0) lo = mid + 1; else hi = mid; }
    const int ibeg = lo;
    hi = N + 1;
    while (lo < hi) { const int mid = (lo + hi) >> 1; if (rowptr[mid] < t1) lo = mid + 1; else hi = mid; }
    const int iend = min(lo, N);

    float accx = 0.f, accy = 0.f;

    if (ibeg < iend) {
        int e = rowptr[ibeg];
        for (int i = ibeg; i < iend; ++i) {
            const int eend = rowptr[i + 1];
            const uint bu = WhU[(size_t)node_ids[i] * 64 + lane];
            float c0x = bflo(bu), c0y = bfhi(bu);
            float c1x = 0.f, c1y = 0.f, c2x = 0.f, c2y = 0.f, c3x = 0.f, c3y = 0.f;
            int ee = e;
            for (; ee + 16 <= eend; ee += 16) {
                uint u[16];
#pragma unroll
                for (int q = 0; q < 16; ++q)
                    u[q] = MhU[(size_t)neighbor_ids[ee + q] * 64 + lane];
#pragma unroll
                for (int q = 0; q < 16; ++q) {
                    switch (q & 3) {
                        case 0: c0x += bflo(u[q]); c0y += bfhi(u[q]); break;
                        case 1: c1x += bflo(u[q]); c1y += bfhi(u[q]); break;
                        case 2: c2x += bflo(u[q]); c2y += bfhi(u[q]); break;
                        default: c3x += bflo(u[q]); c3y += bfhi(u[q]); break;
                    }
                }
            }
            for (; ee + 4 <= eend; ee += 4) {
                const uint v0 = MhU[(size_t)neighbor_ids[ee + 0] * 64 + lane];
                const uint v1 = MhU[(size_t)neighbor_ids[ee + 1] * 64 + lane];
                const uint v2 = MhU[(size_t)neighbor_ids[ee + 2] * 64 + lane];
                const uint v3 = MhU[(size_t)neighbor_ids[ee + 3] * 64 + lane];
                c0x += bflo(v0); c0y += bfhi(v0);
                c1x += bflo(v1); c1y += bfhi(v1);
                c2x += bflo(v2); c2y += bfhi(v2);
                c3x += bflo(v3); c3y += bfhi(v3);
            }
            for (; ee < eend; ++ee) {
                const uint v0 = MhU[(size_t)neighbor_ids[ee] * 64 + lane];
                c0x += bflo(v0); c0y += bfhi(v0);
            }
            const float px = (c0x + c1x) + (c2x + c3x);
            const float py = (c0y + c1y) + (c2y + c3y);
            accx += fmaxf(px, 0.f);
            accy += fmaxf(py, 0.f);
            e = eend;
        }
    }

    __shared__ float red[4][DDIM];
    red[wv][lane * 2 + 0] = accx;
    red[wv][lane * 2 + 1] = accy;
    __syncthreads();
    if (threadIdx.x < DDIM) {
        const float v = red[0][threadIdx.x] + red[1][threadIdx.x]
                      + red[2][threadIdx.x] + red[3][threadIdx.x];
        partials[(size_t)blockIdx.x * DDIM + threadIdx.x] = v;
    }
}

// ---------------- Kernel 3a: grid-parallel partials reduction ----------------
__global__ __launch_bounds__(256) void reduce_partials(
    const float* __restrict__ partials, float* __restrict__ out2, int nb)
{
    const int d = threadIdx.x & (DDIM - 1);
    const int h = threadIdx.x >> 7;
    const int rows = nb / RED_BLOCKS;
    const int r0 = blockIdx.x * rows;
    float s = 0.f;
    for (int r = r0 + h; r < r0 + rows; r += 2)
        s += partials[(size_t)r * DDIM + d];
    __shared__ float red[2][DDIM];
    red[h][d] = s;
    __syncthreads();
    if (threadIdx.x < DDIM)
        out2[(size_t)blockIdx.x * DDIM + threadIdx.x] =
            red[0][threadIdx.x] + red[1][threadIdx.x];
}

// ---------------- Kernel 3b: final reduce (64 rows) + softmax ----------------
__global__ __launch_bounds__(1024) void finalize_softmax(
    const float* __restrict__ p2, float* __restrict__ out, int nb)
{
    const int t = threadIdx.x;
    const int d = t & (DDIM - 1);
    const int g = t >> 7;

    float s = 0.f;
    for (int b = g; b < nb; b += 8)
        s += p2[(size_t)b * DDIM + d];

    __shared__ float red[8][DDIM];
    red[g][d] = s;
    __syncthreads();

    __shared__ float vec[DDIM];
    __shared__ float tmp[DDIM];
    if (g == 0) {
        float v = 0.f;
#pragma unroll
        for (int g2 = 0; g2 < 8; ++g2) v += red[g2][d];
        vec[d] = v;
    }
    __syncthreads();

    const float sv = vec[d];
    if (g == 0) tmp[d] = sv;
    __syncthreads();
    for (int off = 64; off > 0; off >>= 1) {
        if (t < off) tmp[t] = fmaxf(tmp[t], tmp[t + off]);
        __syncthreads();
    }
    const float mx = tmp[0];
    __syncthreads();
    const float ev = expf(sv - mx);
    if (g == 0) tmp[d] = ev;
    __syncthreads();
    for (int off = 64; off > 0; off >>= 1) {
        if (t < off) tmp[t] += tmp[t + off];
        __syncthreads();
    }
    if (g == 0) out[d] = ev / tmp[0];
}

extern "C" void kernel_launch(void* const* d_in, const int* in_sizes, int n_in,
                              void* d_out, int out_size, void* d_ws, size_t ws_size,
                              hipStream_t stream) {
    const float* impact        = (const float*)d_in[0];
    const float* W             = (const float*)d_in[1];
    const float* Mm            = (const float*)d_in[2];
    const int*   node_ids      = (const int*)d_in[3];
    const int*   neighbor_ids  = (const int*)d_in[4];
    const int*   neighbor_segs = (const int*)d_in[5];

    const int T = in_sizes[0] / DDIM;   // 10000
    const int N = in_sizes[3];          // 50000
    const int E = in_sizes[4];          // 800000

    char* ws = (char*)d_ws;
    size_t off = 0;
    ushort* WhB     = (ushort*)(ws + off); off += (size_t)T * DDIM * sizeof(ushort);
    ushort* MhB     = (ushort*)(ws + off); off += (size_t)T * DDIM * sizeof(ushort);
    float* partials = (float*)(ws + off);  off += (size_t)ACC_BLOCKS * DDIM * sizeof(float);
    float* part2    = (float*)(ws + off);  off += (size_t)RED_BLOCKS * DDIM * sizeof(float);
    int*   rowptr   = (int*)(ws + off);    off += (size_t)(N + 1) * sizeof(int);
    float* outf     = (float*)d_out;

    build_rowptr<<<(E + 255) / 256, 256, 0, stream>>>(neighbor_segs, rowptr, N, E);
    precompute_wh_mh<<<(T + 7) / 8, 128, 0, stream>>>(impact, W, Mm, WhB, MhB, T);
    accumulate_nodes<<<ACC_BLOCKS, 256, 0, stream>>>((const uint*)WhB, (const uint*)MhB,
                                                     node_ids, neighbor_ids,
                                                     rowptr, partials, N, E);
    reduce_partials<<<RED_BLOCKS, 256, 0, stream>>>(partials, part2, ACC_BLOCKS);
    finalize_softmax<<<1, 1024, 0, stream>>>(part2, outf, RED_BLOCKS);
}

// Round 8
// 85.386 us; speedup vs baseline: 1.1132x; 1.1132x over previous
//
#include <hip/hip_runtime.h>

#define DDIM 128
#define ACC_BLOCKS 2048
#define RED_BLOCKS 64

typedef unsigned int uint;
typedef unsigned short ushort;

static __device__ __forceinline__ ushort f2bf(float x) {
    uint u = __float_as_uint(x);
    u += 0x7fffu + ((u >> 16) & 1u);   // RTN-even
    return (ushort)(u >> 16);
}
static __device__ __forceinline__ float bflo(uint u) { return __uint_as_float(u << 16); }
static __device__ __forceinline__ float bfhi(uint u) { return __uint_as_float(u & 0xffff0000u); }

// ---------------- Kernel 0: CSR rowptr from sorted segment ids ----------------
__global__ __launch_bounds__(256) void build_rowptr(
    const int* __restrict__ segs, int* __restrict__ rowptr, int N, int E)
{
    const int e = blockIdx.x * blockDim.x + threadIdx.x;
    if (e >= E) return;
    const int sc = segs[e];
    const int sp = (e == 0) ? -1 : segs[e - 1];
    for (int i = sp + 1; i <= sc; ++i) rowptr[i] = e;
    if (e == E - 1) {
        for (int i = sc + 1; i <= N; ++i) rowptr[i] = E;
    }
}

// ---------------- Kernel 0b: unified item stream ----------------
// items[k] = byte offset (within table region) of row to accumulate; bit31 set
// on the LAST item of each node (-> relu flush after adding it).
// Node i's stream slot: rowptr[i]+i (its Wh row), then its edges at e+segs[e]+1.
__global__ __launch_bounds__(256) void build_items(
    const int* __restrict__ segs,
    const int* __restrict__ rowptr,
    const int* __restrict__ node_ids,
    const int* __restrict__ neighbor_ids,
    int* __restrict__ items,
    int N, int E, int whoff, int mhoff)
{
    const int x = blockIdx.x * blockDim.x + threadIdx.x;
    if (x < E) {
        const int s = segs[x];
        const bool last = (x + 1 == E) || (segs[x + 1] != s);
        items[x + s + 1] = (mhoff + neighbor_ids[x] * 256) | (last ? (int)0x80000000 : 0);
    }
    if (x < N) {
        const int r = rowptr[x];
        const bool last = (rowptr[x + 1] == r);     // degree-0 node
        items[r + x] = (whoff + node_ids[x] * 256) | (last ? (int)0x80000000 : 0);
    }
    if (x == 0) {
#pragma unroll
        for (int q = 0; q < 8; ++q) items[N + E + q] = whoff;  // safe pad (masked)
    }
}

// ---------------- Kernel 1: Wh[t]=W@h[t], Mh[t]=M@h[t] -> bf16 tables ----------------
__global__ __launch_bounds__(128) void precompute_wh_mh(
    const float* __restrict__ impact,
    const float* __restrict__ W,
    const float* __restrict__ Mm,
    ushort* __restrict__ WhB,
    ushort* __restrict__ MhB,
    int T)
{
    __shared__ float hrow[8][DDIM];
    const int d = threadIdx.x;
    const int row0 = blockIdx.x * 8;
    const int rmax = min(8, T - row0);
    if (rmax <= 0) return;

    for (int r = 0; r < rmax; ++r)
        hrow[r][d] = impact[(size_t)(row0 + r) * DDIM + d];
    __syncthreads();

    const float4* __restrict__ W4 = reinterpret_cast<const float4*>(W) + (size_t)d * 32;
    const float4* __restrict__ M4 = reinterpret_cast<const float4*>(Mm) + (size_t)d * 32;
    const float4* __restrict__ H4 = reinterpret_cast<const float4*>(&hrow[0][0]);

    float accW[8], accM[8];
#pragma unroll
    for (int r = 0; r < 8; ++r) { accW[r] = 0.f; accM[r] = 0.f; }

    for (int kq = 0; kq < 32; ++kq) {
        const float4 wv = W4[kq];
        const float4 mv = M4[kq];
#pragma unroll
        for (int r = 0; r < 8; ++r) {
            const float4 hv = H4[r * 32 + kq];
            accW[r] = fmaf(hv.x, wv.x, accW[r]);
            accW[r] = fmaf(hv.y, wv.y, accW[r]);
            accW[r] = fmaf(hv.z, wv.z, accW[r]);
            accW[r] = fmaf(hv.w, wv.w, accW[r]);
            accM[r] = fmaf(hv.x, mv.x, accM[r]);
            accM[r] = fmaf(hv.y, mv.y, accM[r]);
            accM[r] = fmaf(hv.z, mv.z, accM[r]);
            accM[r] = fmaf(hv.w, mv.w, accM[r]);
        }
    }
    for (int r = 0; r < rmax; ++r) {
        WhB[(size_t)(row0 + r) * DDIM + d] = f2bf(accW[r]);
        MhB[(size_t)(row0 + r) * DDIM + d] = f2bf(accM[r]);
    }
}

// ---------------- Kernel 2: item-stream gather-accumulate ----------------
// 8 half-wave walkers per block; walker owns a node-snapped, item-balanced
// range [k0,k1) of the stream. Lane = uint2 (4 features). Per 8-chunk: 2x uint4
// item loads + 8 independent row gathers (32-bit offsets, one SGPR base) +
// select-based accumulate/relu-flush. No inner-node loop, no branches.
__global__ __launch_bounds__(256, 8) void accumulate_items(
    const char* __restrict__ tab,
    const int* __restrict__ rowptr,
    const int* __restrict__ items,
    float* __restrict__ partials,
    int N, int K)
{
    const int tid = threadIdx.x;
    const int wb  = tid >> 5;            // walker in block 0..7
    const int fl  = tid & 31;            // feature lane
    const int w   = blockIdx.x * 8 + wb;
    const int NW  = (int)gridDim.x * 8;

    const int t0 = (int)(((long long)w       * K) / NW);
    const int t1 = (int)(((long long)(w + 1) * K) / NW);
    int lo = 0, hi = N;
    while (lo < hi) { const int mid = (lo + hi) >> 1; if (rowptr[mid] + mid < t0) lo = mid + 1; else hi = mid; }
    const int k0 = rowptr[lo] + lo;
    hi = N;
    while (lo < hi) { const int mid = (lo + hi) >> 1; if (rowptr[mid] + mid < t1) lo = mid + 1; else hi = mid; }
    const int k1 = rowptr[lo] + lo;

    const uint foff = (uint)fl * 8u;

    float a0 = 0.f, a1 = 0.f, a2 = 0.f, a3 = 0.f;
    float c0 = 0.f, c1 = 0.f, c2 = 0.f, c3 = 0.f;

    for (int kk = (k0 & ~7); kk < k1; kk += 8) {
        const uint4 ia = *reinterpret_cast<const uint4*>(items + kk);
        const uint4 ib = *reinterpret_cast<const uint4*>(items + kk + 4);
        uint iw[8] = {ia.x, ia.y, ia.z, ia.w, ib.x, ib.y, ib.z, ib.w};
        uint2 v[8];
#pragma unroll
        for (int q = 0; q < 8; ++q) {
            const uint off = (iw[q] & 0x7fffffffu) + foff;
            v[q] = *reinterpret_cast<const uint2*>(tab + off);
        }
#pragma unroll
        for (int q = 0; q < 8; ++q) {
            const int k = kk + q;
            const bool valid = (k >= k0) && (k < k1);
            const uint vx = valid ? v[q].x : 0u;
            const uint vy = valid ? v[q].y : 0u;
            c0 += bflo(vx); c1 += bfhi(vx);
            c2 += bflo(vy); c3 += bfhi(vy);
            const bool flush = valid && ((iw[q] & 0x80000000u) != 0u);
            const float m0 = fmaxf(c0, 0.f), m1 = fmaxf(c1, 0.f);
            const float m2 = fmaxf(c2, 0.f), m3 = fmaxf(c3, 0.f);
            a0 += flush ? m0 : 0.f;  a1 += flush ? m1 : 0.f;
            a2 += flush ? m2 : 0.f;  a3 += flush ? m3 : 0.f;
            c0 = flush ? 0.f : c0;   c1 = flush ? 0.f : c1;
            c2 = flush ? 0.f : c2;   c3 = flush ? 0.f : c3;
        }
    }
    // k1 is a node boundary -> cur already flushed; safety add of relu(0)=0.
    a0 += fmaxf(c0, 0.f); a1 += fmaxf(c1, 0.f);
    a2 += fmaxf(c2, 0.f); a3 += fmaxf(c3, 0.f);

    __shared__ float red[8][DDIM];
    *reinterpret_cast<float4*>(&red[wb][fl * 4]) = make_float4(a0, a1, a2, a3);
    __syncthreads();
    if (tid < DDIM) {
        float s = 0.f;
#pragma unroll
        for (int g = 0; g < 8; ++g) s += red[g][tid];
        partials[(size_t)blockIdx.x * DDIM + tid] = s;
    }
}

// ---------------- Kernel 3a: grid-parallel partials reduction ----------------
__global__ __launch_bounds__(256) void reduce_partials(
    const float* __restrict__ partials, float* __restrict__ out2, int nb)
{
    const int d = threadIdx.x & (DDIM - 1);
    const int h = threadIdx.x >> 7;
    const int rows = nb / RED_BLOCKS;
    const int r0 = blockIdx.x * rows;
    float s = 0.f;
    for (int r = r0 + h; r < r0 + rows; r += 2)
        s += partials[(size_t)r * DDIM + d];
    __shared__ float red[2][DDIM];
    red[h][d] = s;
    __syncthreads();
    if (threadIdx.x < DDIM)
        out2[(size_t)blockIdx.x * DDIM + threadIdx.x] =
            red[0][threadIdx.x] + red[1][threadIdx.x];
}

// ---------------- Kernel 3b: final reduce + softmax ----------------
__global__ __launch_bounds__(1024) void finalize_softmax(
    const float* __restrict__ p2, float* __restrict__ out, int nb)
{
    const int t = threadIdx.x;
    const int d = t & (DDIM - 1);
    const int g = t >> 7;

    float s = 0.f;
    for (int b = g; b < nb; b += 8)
        s += p2[(size_t)b * DDIM + d];

    __shared__ float red[8][DDIM];
    red[g][d] = s;
    __syncthreads();

    __shared__ float vec[DDIM];
    __shared__ float tmp[DDIM];
    if (g == 0) {
        float v = 0.f;
#pragma unroll
        for (int g2 = 0; g2 < 8; ++g2) v += red[g2][d];
        vec[d] = v;
    }
    __syncthreads();

    const float sv = vec[d];
    if (g == 0) tmp[d] = sv;
    __syncthreads();
    for (int off = 64; off > 0; off >>= 1) {
        if (t < off) tmp[t] = fmaxf(tmp[t], tmp[t + off]);
        __syncthreads();
    }
    const float mx = tmp[0];
    __syncthreads();
    const float ev = expf(sv - mx);
    if (g == 0) tmp[d] = ev;
    __syncthreads();
    for (int off = 64; off > 0; off >>= 1) {
        if (t < off) tmp[t] += tmp[t + off];
        __syncthreads();
    }
    if (g == 0) out[d] = ev / tmp[0];
}

extern "C" void kernel_launch(void* const* d_in, const int* in_sizes, int n_in,
                              void* d_out, int out_size, void* d_ws, size_t ws_size,
                              hipStream_t stream) {
    const float* impact        = (const float*)d_in[0];
    const float* W             = (const float*)d_in[1];
    const float* Mm            = (const float*)d_in[2];
    const int*   node_ids      = (const int*)d_in[3];
    const int*   neighbor_ids  = (const int*)d_in[4];
    const int*   neighbor_segs = (const int*)d_in[5];

    const int T = in_sizes[0] / DDIM;   // 10000
    const int N = in_sizes[3];          // 50000
    const int E = in_sizes[4];          // 800000
    const int K = N + E;

    char* ws = (char*)d_ws;
    size_t off = 0;
    const int whoff = (int)off;
    ushort* WhB = (ushort*)(ws + off);  off += (size_t)T * DDIM * sizeof(ushort);   // 2.56 MB
    const int mhoff = (int)off;
    ushort* MhB = (ushort*)(ws + off);  off += (size_t)T * DDIM * sizeof(ushort);   // 2.56 MB
    float* partials = (float*)(ws + off); off += (size_t)ACC_BLOCKS * DDIM * sizeof(float);
    float* part2    = (float*)(ws + off); off += (size_t)RED_BLOCKS * DDIM * sizeof(float);
    int*   rowptr   = (int*)(ws + off);   off += (size_t)(N + 1) * sizeof(int);
    off = (off + 255) & ~(size_t)255;                      // 16B+ align for uint4 item loads
    int*   items    = (int*)(ws + off);   off += (size_t)(K + 8) * sizeof(int);
    float* outf     = (float*)d_out;

    build_rowptr<<<(E + 255) / 256, 256, 0, stream>>>(neighbor_segs, rowptr, N, E);
    build_items<<<(max(E, N) + 255) / 256, 256, 0, stream>>>(
        neighbor_segs, rowptr, node_ids, neighbor_ids, items, N, E, whoff, mhoff);
    precompute_wh_mh<<<(T + 7) / 8, 128, 0, stream>>>(impact, W, Mm, WhB, MhB, T);
    accumulate_items<<<ACC_BLOCKS, 256, 0, stream>>>(ws, rowptr, items, partials, N, K);
    reduce_partials<<<RED_BLOCKS, 256, 0, stream>>>(partials, part2, ACC_BLOCKS);
    finalize_softmax<<<1, 1024, 0, stream>>>(part2, outf, RED_BLOCKS);
}

// Round 9
// 68.078 us; speedup vs baseline: 1.3963x; 1.2542x over previous
//
#include <hip/hip_runtime.h>

#define DDIM 128
#define ACC_BLOCKS 2048
#define NWALK (ACC_BLOCKS * 4)     // one full wave per walker
#define RED_BLOCKS 64

typedef unsigned int uint;
typedef unsigned short ushort;

static __device__ __forceinline__ ushort f2bf(float x) {
    uint u = __float_as_uint(x);
    u += 0x7fffu + ((u >> 16) & 1u);   // RTN-even
    return (ushort)(u >> 16);
}
static __device__ __forceinline__ float bflo(uint u) { return __uint_as_float(u << 16); }
static __device__ __forceinline__ float bfhi(uint u) { return __uint_as_float(u & 0xffff0000u); }

// ---------------- Kernel 0: CSR rowptr from sorted segment ids ----------------
__global__ __launch_bounds__(256) void build_rowptr(
    const int* __restrict__ segs, int* __restrict__ rowptr, int N, int E)
{
    const int e = blockIdx.x * blockDim.x + threadIdx.x;
    if (e >= E) return;
    const int sc = segs[e];
    const int sp = (e == 0) ? -1 : segs[e - 1];
    for (int i = sp + 1; i <= sc; ++i) rowptr[i] = e;
    if (e == E - 1) {
        for (int i = sc + 1; i <= N; ++i) rowptr[i] = E;
    }
}

// ---------------- Kernel 0b: unified item stream + walker start table ----------------
// items[k] = byte offset of row to accumulate; bit31 = last item of node (relu flush).
// Node i occupies slots [rowptr[i]+i, rowptr[i+1]+i]: Wh row first, then its edges.
// wstart[w] = node-snapped stream position for walker w (equal-item spacing).
__global__ __launch_bounds__(256) void build_items(
    const int* __restrict__ segs,
    const int* __restrict__ rowptr,
    const int* __restrict__ node_ids,
    const int* __restrict__ neighbor_ids,
    int* __restrict__ items,
    int* __restrict__ wstart,
    int N, int E, int whoff, int mhoff)
{
    const int x = blockIdx.x * blockDim.x + threadIdx.x;
    const int K = N + E;
    if (x < E) {
        const int s = segs[x];
        const bool last = (x + 1 == E) || (segs[x + 1] != s);
        items[x + s + 1] = (mhoff + neighbor_ids[x] * 256) | (last ? (int)0x80000000 : 0);
    }
    if (x < N) {
        const int r = rowptr[x];
        const bool last = (rowptr[x + 1] == r);     // degree-0 node
        items[r + x] = (whoff + node_ids[x] * 256) | (last ? (int)0x80000000 : 0);
    }
    if (x <= NWALK) {
        const int t = (int)(((long long)x * K) / NWALK);
        int lo = 0, hi = N;
        while (lo < hi) {
            const int mid = (lo + hi) >> 1;
            if (rowptr[mid] + mid < t) lo = mid + 1; else hi = mid;
        }
        wstart[x] = rowptr[lo] + lo;                // lo==N -> E+N = K
    }
    if (x == 0) {
#pragma unroll
        for (int q = 0; q < 8; ++q) items[K + q] = whoff;  // pad (never flushed)
    }
}

// ---------------- Kernel 1: Wh[t]=W@h[t], Mh[t]=M@h[t] -> bf16 tables ----------------
// h rows are wave-uniform -> s_load float4 (scalar pipe), FMA with SGPR operand.
// No LDS, no __syncthreads. Thread d streams its W/M rows as float4.
__global__ __launch_bounds__(128) void precompute_wh_mh(
    const float* __restrict__ impact,
    const float* __restrict__ W,
    const float* __restrict__ Mm,
    ushort* __restrict__ WhB,
    ushort* __restrict__ MhB,
    int T)
{
    const int d = threadIdx.x;
    const int row0 = blockIdx.x * 8;
    if (row0 >= T) return;
    const int rmax = min(8, T - row0);

    const float4* __restrict__ W4 = reinterpret_cast<const float4*>(W) + (size_t)d * 32;
    const float4* __restrict__ M4 = reinterpret_cast<const float4*>(Mm) + (size_t)d * 32;
    const float4* __restrict__ H4 = reinterpret_cast<const float4*>(impact);  // [T][32]

    float accW[8], accM[8];
#pragma unroll
    for (int r = 0; r < 8; ++r) { accW[r] = 0.f; accM[r] = 0.f; }

    for (int kq = 0; kq < 32; ++kq) {
        const float4 wv = W4[kq];
        const float4 mv = M4[kq];
#pragma unroll
        for (int r = 0; r < 8; ++r) {
            const int rr = (r < rmax) ? (row0 + r) : (T - 1);   // clamp (uniform)
            const float4 hv = H4[(size_t)rr * 32 + kq];         // uniform -> s_load
            accW[r] = fmaf(hv.x, wv.x, accW[r]);
            accW[r] = fmaf(hv.y, wv.y, accW[r]);
            accW[r] = fmaf(hv.z, wv.z, accW[r]);
            accW[r] = fmaf(hv.w, wv.w, accW[r]);
            accM[r] = fmaf(hv.x, mv.x, accM[r]);
            accM[r] = fmaf(hv.y, mv.y, accM[r]);
            accM[r] = fmaf(hv.z, mv.z, accM[r]);
            accM[r] = fmaf(hv.w, mv.w, accM[r]);
        }
    }
    for (int r = 0; r < rmax; ++r) {
        WhB[(size_t)(row0 + r) * DDIM + d] = f2bf(accW[r]);
        MhB[(size_t)(row0 + r) * DDIM + d] = f2bf(accM[r]);
    }
}

// ---------------- Kernel 2: item-stream gather-accumulate (full-wave walkers) ----------------
// One wave per walker. Item words live in SGPRs (scalar loads, wave-uniform k);
// gathers are saddr-form (SGPR row base + fixed lane*4 VGPR offset); flush is a
// wave-uniform scalar branch. Lane = 1 uint = 2 bf16 features, fp32 accumulate.
__global__ __launch_bounds__(256, 8) void accumulate_items(
    const char* __restrict__ tab,
    const int* __restrict__ items,
    const int* __restrict__ wstart,
    float* __restrict__ partials)
{
    const int lane = threadIdx.x & 63;
    const int wv   = __builtin_amdgcn_readfirstlane(threadIdx.x >> 6);
    const int w    = blockIdx.x * 4 + wv;

    const uint lb = (uint)lane << 2;

    float c0 = 0.f, c1 = 0.f, a0 = 0.f, a1 = 0.f;

    int k    = __builtin_amdgcn_readfirstlane(wstart[w]);
    const int kend = __builtin_amdgcn_readfirstlane(wstart[w + 1]);

#define LDROW(IW) (*reinterpret_cast<const uint*>(tab + (((uint)(IW)) & 0x7fffffffu) + lb))
#define ACC(IW, V) { \
    c0 += bflo(V); c1 += bfhi(V); \
    if ((IW) < 0) { a0 += fmaxf(c0, 0.f); a1 += fmaxf(c1, 0.f); c0 = 0.f; c1 = 0.f; } }

    // head: align k to 8 (uniform control)
    while (k < kend && (k & 7)) {
        const int iw = items[k];
        const uint v = LDROW(iw);
        ACC(iw, v);
        ++k;
    }
    // body: 8 items per iter; loads issued as a batch (8 outstanding per wave)
    while (k + 8 <= kend) {
        const int4 A = *reinterpret_cast<const int4*>(items + k);
        const int4 B = *reinterpret_cast<const int4*>(items + k + 4);
        const uint v0 = LDROW(A.x);
        const uint v1 = LDROW(A.y);
        const uint v2 = LDROW(A.z);
        const uint v3 = LDROW(A.w);
        const uint v4 = LDROW(B.x);
        const uint v5 = LDROW(B.y);
        const uint v6 = LDROW(B.z);
        const uint v7 = LDROW(B.w);
        ACC(A.x, v0); ACC(A.y, v1); ACC(A.z, v2); ACC(A.w, v3);
        ACC(B.x, v4); ACC(B.y, v5); ACC(B.z, v6); ACC(B.w, v7);
        k += 8;
    }
    // tail
    while (k < kend) {
        const int iw = items[k];
        const uint v = LDROW(iw);
        ACC(iw, v);
        ++k;
    }

    // range ends at a node boundary -> c==0; safe relu(0) add.
    a0 += fmaxf(c0, 0.f);
    a1 += fmaxf(c1, 0.f);

    __shared__ float red[4][DDIM];
    red[wv][lane * 2 + 0] = a0;
    red[wv][lane * 2 + 1] = a1;
    __syncthreads();
    const int tid = threadIdx.x;
    if (tid < DDIM) {
        partials[(size_t)blockIdx.x * DDIM + tid] =
            red[0][tid] + red[1][tid] + red[2][tid] + red[3][tid];
    }
}

// ---------------- Kernel 3a: grid-parallel partials reduction ----------------
__global__ __launch_bounds__(256) void reduce_partials(
    const float* __restrict__ partials, float* __restrict__ out2, int nb)
{
    const int d = threadIdx.x & (DDIM - 1);
    const int h = threadIdx.x >> 7;
    const int rows = nb / RED_BLOCKS;
    const int r0 = blockIdx.x * rows;
    float s = 0.f;
    for (int r = r0 + h; r < r0 + rows; r += 2)
        s += partials[(size_t)r * DDIM + d];
    __shared__ float red[2][DDIM];
    red[h][d] = s;
    __syncthreads();
    if (threadIdx.x < DDIM)
        out2[(size_t)blockIdx.x * DDIM + threadIdx.x] =
            red[0][threadIdx.x] + red[1][threadIdx.x];
}

// ---------------- Kernel 3b: final reduce + softmax ----------------
__global__ __launch_bounds__(1024) void finalize_softmax(
    const float* __restrict__ p2, float* __restrict__ out, int nb)
{
    const int t = threadIdx.x;
    const int d = t & (DDIM - 1);
    const int g = t >> 7;

    float s = 0.f;
    for (int b = g; b < nb; b += 8)
        s += p2[(size_t)b * DDIM + d];

    __shared__ float red[8][DDIM];
    red[g][d] = s;
    __syncthreads();

    __shared__ float vec[DDIM];
    __shared__ float tmp[DDIM];
    if (g == 0) {
        float v = 0.f;
#pragma unroll
        for (int g2 = 0; g2 < 8; ++g2) v += red[g2][d];
        vec[d] = v;
    }
    __syncthreads();

    const float sv = vec[d];
    if (g == 0) tmp[d] = sv;
    __syncthreads();
    for (int off = 64; off > 0; off >>= 1) {
        if (t < off) tmp[t] = fmaxf(tmp[t], tmp[t + off]);
        __syncthreads();
    }
    const float mx = tmp[0];
    __syncthreads();
    const float ev = expf(sv - mx);
    if (g == 0) tmp[d] = ev;
    __syncthreads();
    for (int off = 64; off > 0; off >>= 1) {
        if (t < off) tmp[t] += tmp[t + off];
        __syncthreads();
    }
    if (g == 0) out[d] = ev / tmp[0];
}

extern "C" void kernel_launch(void* const* d_in, const int* in_sizes, int n_in,
                              void* d_out, int out_size, void* d_ws, size_t ws_size,
                              hipStream_t stream) {
    const float* impact        = (const float*)d_in[0];
    const float* W             = (const float*)d_in[1];
    const float* Mm            = (const float*)d_in[2];
    const int*   node_ids      = (const int*)d_in[3];
    const int*   neighbor_ids  = (const int*)d_in[4];
    const int*   neighbor_segs = (const int*)d_in[5];

    const int T = in_sizes[0] / DDIM;   // 10000
    const int N = in_sizes[3];          // 50000
    const int E = in_sizes[4];          // 800000
    const int K = N + E;

    char* ws = (char*)d_ws;
    size_t off = 0;
    const int whoff = (int)off;
    ushort* WhB = (ushort*)(ws + off);  off += (size_t)T * DDIM * sizeof(ushort);   // 2.56 MB
    const int mhoff = (int)off;
    ushort* MhB = (ushort*)(ws + off);  off += (size_t)T * DDIM * sizeof(ushort);   // 2.56 MB
    float* partials = (float*)(ws + off); off += (size_t)ACC_BLOCKS * DDIM * sizeof(float);
    float* part2    = (float*)(ws + off); off += (size_t)RED_BLOCKS * DDIM * sizeof(float);
    int*   rowptr   = (int*)(ws + off);   off += (size_t)(N + 1) * sizeof(int);
    off = (off + 255) & ~(size_t)255;                      // align for int4 item loads
    int*   items    = (int*)(ws + off);   off += (size_t)(K + 8) * sizeof(int);
    int*   wstart   = (int*)(ws + off);   off += (size_t)(NWALK + 1) * sizeof(int);
    float* outf     = (float*)d_out;

    build_rowptr<<<(E + 255) / 256, 256, 0, stream>>>(neighbor_segs, rowptr, N, E);
    build_items<<<(max(E, N) + 255) / 256, 256, 0, stream>>>(
        neighbor_segs, rowptr, node_ids, neighbor_ids, items, wstart, N, E, whoff, mhoff);
    precompute_wh_mh<<<(T + 7) / 8, 128, 0, stream>>>(impact, W, Mm, WhB, MhB, T);
    accumulate_items<<<ACC_BLOCKS, 256, 0, stream>>>(ws, items, wstart, partials);
    reduce_partials<<<RED_BLOCKS, 256, 0, stream>>>(partials, part2, ACC_BLOCKS);
    finalize_softmax<<<1, 1024, 0, stream>>>(part2, outf, RED_BLOCKS);
}

// Round 10
// 66.043 us; speedup vs baseline: 1.4393x; 1.0308x over previous
//
#include <hip/hip_runtime.h>

#define DDIM 128
#define ACC_BLOCKS 2048
#define NWALK (ACC_BLOCKS * 4)
#define RED_BLOCKS 64

typedef unsigned int uint;
typedef unsigned short ushort;
typedef __attribute__((ext_vector_type(8))) short bf16x8;
typedef __attribute__((ext_vector_type(4))) float f32x4;

static __device__ __forceinline__ ushort f2bf(float x) {
    uint u = __float_as_uint(x);
    u += 0x7fffu + ((u >> 16) & 1u);   // RTN-even
    return (ushort)(u >> 16);
}
static __device__ __forceinline__ float bflo(uint u) { return __uint_as_float(u << 16); }
static __device__ __forceinline__ float bfhi(uint u) { return __uint_as_float(u & 0xffff0000u); }

// ---------------- Kernel 0: CSR rowptr + zero done-counter ----------------
__global__ __launch_bounds__(256) void build_rowptr(
    const int* __restrict__ segs, int* __restrict__ rowptr, int* __restrict__ done,
    int N, int E)
{
    const int e = blockIdx.x * blockDim.x + threadIdx.x;
    if (e == 0) *done = 0;
    if (e >= E) return;
    const int sc = segs[e];
    const int sp = (e == 0) ? -1 : segs[e - 1];
    for (int i = sp + 1; i <= sc; ++i) rowptr[i] = e;
    if (e == E - 1) {
        for (int i = sc + 1; i <= N; ++i) rowptr[i] = E;
    }
}

// ---------------- Kernel 0b: unified item stream + walker start table ----------------
__global__ __launch_bounds__(256) void build_items(
    const int* __restrict__ segs,
    const int* __restrict__ rowptr,
    const int* __restrict__ node_ids,
    const int* __restrict__ neighbor_ids,
    int* __restrict__ items,
    int* __restrict__ wstart,
    int N, int E, int whoff, int mhoff)
{
    const int x = blockIdx.x * blockDim.x + threadIdx.x;
    const int K = N + E;
    if (x < E) {
        const int s = segs[x];
        const bool last = (x + 1 == E) || (segs[x + 1] != s);
        items[x + s + 1] = (mhoff + neighbor_ids[x] * 256) | (last ? (int)0x80000000 : 0);
    }
    if (x < N) {
        const int r = rowptr[x];
        const bool last = (rowptr[x + 1] == r);     // degree-0 node
        items[r + x] = (whoff + node_ids[x] * 256) | (last ? (int)0x80000000 : 0);
    }
    if (x <= NWALK) {
        const int t = (int)(((long long)x * K) / NWALK);
        int lo = 0, hi = N;
        while (lo < hi) {
            const int mid = (lo + hi) >> 1;
            if (rowptr[mid] + mid < t) lo = mid + 1; else hi = mid;
        }
        wstart[x] = rowptr[lo] + lo;
    }
    if (x == 0) {
#pragma unroll
        for (int q = 0; q < 16; ++q) items[K + q] = whoff;  // pad (never flushed)
    }
}

// ---------------- Kernel 1: MFMA precompute Wh/Mh (bf16 tables) ----------------
// Wave: 32 t-rows x 32 d-cols, K=128 via 4x mfma_f32_16x16x32_bf16 per (tile,mat).
// A: impact rows (fp32->bf16), row=lane&15, k=(lane>>4)*8+j.
// B: W/M rows (B^T layout), col=lane&15, same k mapping.
// C/D: row=(lane>>4)*4+reg, col=lane&15 (docs-verified).
static __device__ __forceinline__ bf16x8 load_frag8(const float* base) {
    const float4 p = *reinterpret_cast<const float4*>(base);
    const float4 q = *reinterpret_cast<const float4*>(base + 4);
    bf16x8 f;
    f[0] = (short)f2bf(p.x); f[1] = (short)f2bf(p.y);
    f[2] = (short)f2bf(p.z); f[3] = (short)f2bf(p.w);
    f[4] = (short)f2bf(q.x); f[5] = (short)f2bf(q.y);
    f[6] = (short)f2bf(q.z); f[7] = (short)f2bf(q.w);
    return f;
}

__global__ __launch_bounds__(256) void precompute_mfma(
    const float* __restrict__ impact,
    const float* __restrict__ W,
    const float* __restrict__ Mm,
    ushort* __restrict__ WhB,
    ushort* __restrict__ MhB,
    int T)
{
    const int lane = threadIdx.x & 63;
    const int wv   = threadIdx.x >> 6;       // 0..3 -> d tiles {2wv, 2wv+1}
    const int t0   = blockIdx.x * 32;
    const int r16  = lane & 15;
    const int kg   = lane >> 4;              // 0..3

    bf16x8 A[2][4];
#pragma unroll
    for (int rt = 0; rt < 2; ++rt) {
        int t = t0 + rt * 16 + r16;
        if (t >= T) t = T - 1;               // clamp; writes masked below
        const float* abase = impact + (size_t)t * DDIM + kg * 8;
#pragma unroll
        for (int k0i = 0; k0i < 4; ++k0i)
            A[rt][k0i] = load_frag8(abase + k0i * 32);
    }

#pragma unroll
    for (int dti = 0; dti < 2; ++dti) {
        const int d0 = (wv * 2 + dti) * 16;
#pragma unroll
        for (int m = 0; m < 2; ++m) {
            const float* mat = (m == 0) ? W : Mm;
            ushort* out = (m == 0) ? WhB : MhB;
            const float* bbase = mat + (size_t)(d0 + r16) * DDIM + kg * 8;
            f32x4 acc0 = {0.f, 0.f, 0.f, 0.f};
            f32x4 acc1 = {0.f, 0.f, 0.f, 0.f};
#pragma unroll
            for (int k0i = 0; k0i < 4; ++k0i) {
                const bf16x8 b = load_frag8(bbase + k0i * 32);
                acc0 = __builtin_amdgcn_mfma_f32_16x16x32_bf16(A[0][k0i], b, acc0, 0, 0, 0);
                acc1 = __builtin_amdgcn_mfma_f32_16x16x32_bf16(A[1][k0i], b, acc1, 0, 0, 0);
            }
            const int dcol = d0 + r16;
#pragma unroll
            for (int r = 0; r < 4; ++r) {
                const int tr0 = t0 + kg * 4 + r;
                const int tr1 = tr0 + 16;
                if (tr0 < T) out[(size_t)tr0 * DDIM + dcol] = f2bf(acc0[r]);
                if (tr1 < T) out[(size_t)tr1 * DDIM + dcol] = f2bf(acc1[r]);
            }
        }
    }
}

// ---------------- Kernel 2: item-stream gather-accumulate (full-wave walkers) ----------------
__global__ __launch_bounds__(256, 8) void accumulate_items(
    const char* __restrict__ tab,
    const int* __restrict__ items,
    const int* __restrict__ wstart,
    float* __restrict__ partials)
{
    const int lane = threadIdx.x & 63;
    const int wv   = __builtin_amdgcn_readfirstlane(threadIdx.x >> 6);
    const int w    = blockIdx.x * 4 + wv;

    const uint lb = (uint)lane << 2;

    float c0 = 0.f, c1 = 0.f, a0 = 0.f, a1 = 0.f;

    int k = __builtin_amdgcn_readfirstlane(wstart[w]);
    const int kend = __builtin_amdgcn_readfirstlane(wstart[w + 1]);

#define LDROW(IW) (*reinterpret_cast<const uint*>(tab + (((uint)(IW)) & 0x7fffffffu) + lb))
#define ACC(IW, V) { \
    c0 += bflo(V); c1 += bfhi(V); \
    if ((IW) < 0) { a0 += fmaxf(c0, 0.f); a1 += fmaxf(c1, 0.f); c0 = 0.f; c1 = 0.f; } }

    // head: align k to 4 (int4 alignment)
    while (k < kend && (k & 3)) {
        const int iw = items[k];
        const uint v = LDROW(iw);
        ACC(iw, v);
        ++k;
    }
    // body: 16 items per iter, 16 gathers in flight
    while (k + 16 <= kend) {
        const int4 Ia = *reinterpret_cast<const int4*>(items + k);
        const int4 Ib = *reinterpret_cast<const int4*>(items + k + 4);
        const int4 Ic = *reinterpret_cast<const int4*>(items + k + 8);
        const int4 Id = *reinterpret_cast<const int4*>(items + k + 12);
        const uint v0  = LDROW(Ia.x); const uint v1  = LDROW(Ia.y);
        const uint v2  = LDROW(Ia.z); const uint v3  = LDROW(Ia.w);
        const uint v4  = LDROW(Ib.x); const uint v5  = LDROW(Ib.y);
        const uint v6  = LDROW(Ib.z); const uint v7  = LDROW(Ib.w);
        const uint v8  = LDROW(Ic.x); const uint v9  = LDROW(Ic.y);
        const uint v10 = LDROW(Ic.z); const uint v11 = LDROW(Ic.w);
        const uint v12 = LDROW(Id.x); const uint v13 = LDROW(Id.y);
        const uint v14 = LDROW(Id.z); const uint v15 = LDROW(Id.w);
        ACC(Ia.x, v0);  ACC(Ia.y, v1);  ACC(Ia.z, v2);  ACC(Ia.w, v3);
        ACC(Ib.x, v4);  ACC(Ib.y, v5);  ACC(Ib.z, v6);  ACC(Ib.w, v7);
        ACC(Ic.x, v8);  ACC(Ic.y, v9);  ACC(Ic.z, v10); ACC(Ic.w, v11);
        ACC(Id.x, v12); ACC(Id.y, v13); ACC(Id.z, v14); ACC(Id.w, v15);
        k += 16;
    }
    // mid tail: 4 at a time
    while (k + 4 <= kend) {
        const int4 Ia = *reinterpret_cast<const int4*>(items + k);
        const uint v0 = LDROW(Ia.x); const uint v1 = LDROW(Ia.y);
        const uint v2 = LDROW(Ia.z); const uint v3 = LDROW(Ia.w);
        ACC(Ia.x, v0); ACC(Ia.y, v1); ACC(Ia.z, v2); ACC(Ia.w, v3);
        k += 4;
    }
    // tail
    while (k < kend) {
        const int iw = items[k];
        const uint v = LDROW(iw);
        ACC(iw, v);
        ++k;
    }

    a0 += fmaxf(c0, 0.f);   // range ends at node boundary -> c==0; relu(0)=0 safe
    a1 += fmaxf(c1, 0.f);

    __shared__ float red[4][DDIM];
    red[wv][lane * 2 + 0] = a0;
    red[wv][lane * 2 + 1] = a1;
    __syncthreads();
    const int tid = threadIdx.x;
    if (tid < DDIM) {
        partials[(size_t)blockIdx.x * DDIM + tid] =
            red[0][tid] + red[1][tid] + red[2][tid] + red[3][tid];
    }
}

// ---------------- Kernel 3: reduce partials + last-block softmax ----------------
__global__ __launch_bounds__(256) void reduce_softmax(
    const float* __restrict__ partials, float* __restrict__ out2,
    float* __restrict__ out, int* __restrict__ done, int nb)
{
    const int tid = threadIdx.x;
    const int d = tid & (DDIM - 1);
    const int h = tid >> 7;                  // 0..1
    {
        const int rows = nb / RED_BLOCKS;    // 32
        const int r0 = blockIdx.x * rows;
        float s = 0.f;
        for (int r = r0 + h; r < r0 + rows; r += 2)
            s += partials[(size_t)r * DDIM + d];
        __shared__ float red[2][DDIM];
        red[h][d] = s;
        __syncthreads();
        if (tid < DDIM)
            out2[(size_t)blockIdx.x * DDIM + tid] = red[0][tid] + red[1][tid];
    }
    __threadfence();
    __shared__ int isLast;
    if (tid == 0) {
        const int v = atomicAdd(done, 1);
        isLast = (v == RED_BLOCKS - 1) ? 1 : 0;
    }
    __syncthreads();
    if (!isLast) return;
    __threadfence();                          // acquire

    float s = 0.f;
    for (int b = h; b < RED_BLOCKS; b += 2)
        s += out2[(size_t)b * DDIM + d];
    __shared__ float r2[2][DDIM];
    r2[h][d] = s;
    __syncthreads();

    __shared__ float vec[DDIM];
    __shared__ float tmp[DDIM];
    if (tid < DDIM) { vec[tid] = r2[0][tid] + r2[1][tid]; tmp[tid] = r2[0][tid] + r2[1][tid]; }
    __syncthreads();
    for (int o = 64; o > 0; o >>= 1) {
        if (tid < o) tmp[tid] = fmaxf(tmp[tid], tmp[tid + o]);
        __syncthreads();
    }
    const float mx = tmp[0];
    __syncthreads();
    float ev = 0.f;
    if (tid < DDIM) { ev = expf(vec[tid] - mx); tmp[tid] = ev; }
    __syncthreads();
    for (int o = 64; o > 0; o >>= 1) {
        if (tid < o) tmp[tid] += tmp[tid + o];
        __syncthreads();
    }
    if (tid < DDIM) out[tid] = ev / tmp[0];
}

extern "C" void kernel_launch(void* const* d_in, const int* in_sizes, int n_in,
                              void* d_out, int out_size, void* d_ws, size_t ws_size,
                              hipStream_t stream) {
    const float* impact        = (const float*)d_in[0];
    const float* W             = (const float*)d_in[1];
    const float* Mm            = (const float*)d_in[2];
    const int*   node_ids      = (const int*)d_in[3];
    const int*   neighbor_ids  = (const int*)d_in[4];
    const int*   neighbor_segs = (const int*)d_in[5];

    const int T = in_sizes[0] / DDIM;   // 10000
    const int N = in_sizes[3];          // 50000
    const int E = in_sizes[4];          // 800000
    const int K = N + E;

    char* ws = (char*)d_ws;
    size_t off = 0;
    const int whoff = (int)off;
    ushort* WhB = (ushort*)(ws + off);  off += (size_t)T * DDIM * sizeof(ushort);   // 2.56 MB
    const int mhoff = (int)off;
    ushort* MhB = (ushort*)(ws + off);  off += (size_t)T * DDIM * sizeof(ushort);   // 2.56 MB
    float* partials = (float*)(ws + off); off += (size_t)ACC_BLOCKS * DDIM * sizeof(float);
    float* part2    = (float*)(ws + off); off += (size_t)RED_BLOCKS * DDIM * sizeof(float);
    int*   rowptr   = (int*)(ws + off);   off += (size_t)(N + 1) * sizeof(int);
    int*   done     = (int*)(ws + off);   off += 256;            // counter (padded)
    off = (off + 255) & ~(size_t)255;                            // align for int4 item loads
    int*   items    = (int*)(ws + off);   off += (size_t)(K + 16) * sizeof(int);
    int*   wstart   = (int*)(ws + off);   off += (size_t)(NWALK + 1) * sizeof(int);
    float* outf     = (float*)d_out;

    build_rowptr<<<(E + 255) / 256, 256, 0, stream>>>(neighbor_segs, rowptr, done, N, E);
    build_items<<<(max(E, N) + 255) / 256, 256, 0, stream>>>(
        neighbor_segs, rowptr, node_ids, neighbor_ids, items, wstart, N, E, whoff, mhoff);
    precompute_mfma<<<(T + 31) / 32, 256, 0, stream>>>(impact, W, Mm, WhB, MhB, T);
    accumulate_items<<<ACC_BLOCKS, 256, 0, stream>>>(ws, items, wstart, partials);
    reduce_softmax<<<RED_BLOCKS, 256, 0, stream>>>(partials, part2, outf, done, ACC_BLOCKS);
}